// Round 5
// baseline (100.774 us; speedup 1.0000x reference)
//
#include <hip/hip_runtime.h>

// Chamfer distance, B=16 clouds x N=4096 x D=3, fp32, via bf16-split MFMA.
// S_ij = d(x_i, y_j) computed by ONE v_mfma_f32_32x32x16_bf16 dot (K=16):
//   A_i = [xh0..2, xl0..2, xh0..2, x2h, x2l, 1, 1, xl0..2]
//   B_j = [-2yh0..2, -2yh0..2, -2yl0..2, 1, 1, y2h, y2l, -2yl0..2]
//   sum_k A_ik B_jk = x^2 + y^2 - 2(xh+xl).(yh+yl)  (abs err <~7e-4)
// One S serves both directions: row-mins -> cham_x, col-mins -> cham_y.
// R8: j sliced 4-way, Bb from global with 1-iter prefetch. 96us.
// R9/R10: fused reduce w/ device atomics+fences. REGRESSION 137us. Reverted.
// R11: + v_min3 trees: 98.5us, NEUTRAL -> not VALU-throughput-bound.
// R12: __launch_bounds__(256,5) -> FAILED (absmax ~1e15 = workspace poison;
//   cd_mfma never ran). Lesson: no forced min-waves on this kernel.
// R13: theory = per-iter global B loads stall on L2 latency (~250cy) with
//   ~100cy of prefetch slack; all waves stall in lockstep (VALUBusy 33%,
//   MfmaUtil 4%). Fix: fuse prep into cd_mfma. A-rows built per-lane in
//   regs from pred; B-slice (512 pts) bf16-split into 16KB LDS once, then
//   ds_read_b128 (XOR-swizzled: bit4 ^= point&7, invariant over j-loop,
//   same XOR on write+read). kJS 4->8, 4096 blocks, 24KB LDS (6 blk/CU).
//   cd_prep eliminated (launch + 6MB write + 10.5MB re-read); out[0]
//   zeroed by block(0,0,0) (stream-ordered before cd_reduce). 3->2 launches.

namespace {

constexpr int kB = 16;
constexpr int kN = 4096;
constexpr int kPlane = kB * kN;
constexpr int kJS = 8;                    // j-slices
constexpr int kJSL = kN / kJS;            // 512 j per slice
constexpr float kScale = 1.0f / (float)(kB * kN);

typedef short bf16x8 __attribute__((ext_vector_type(8)));
typedef float f32x16 __attribute__((ext_vector_type(16)));
typedef unsigned short u16;

__device__ inline u16 bf16_rn(float f) {
  union { float f; unsigned u; } v; v.f = f;
  unsigned r = v.u + 0x7fffu + ((v.u >> 16) & 1u);
  return (u16)(r >> 16);
}
__device__ inline float bf16_f(u16 h) {
  union { unsigned u; float f; } v; v.u = (unsigned)h << 16;
  return v.f;
}
__device__ inline unsigned pk2(u16 lo, u16 hi) {
  return (unsigned)lo | ((unsigned)hi << 16);
}

__device__ inline float min3f(float a, float b, float c) {
  float d;
  asm("v_min3_f32 %0, %1, %2, %3" : "=v"(d) : "v"(a), "v"(b), "v"(c));
  return d;
}

__global__ void init_out(float* out) { out[0] = 0.0f; }

// Fused prep + MFMA. Block = 4 waves; wave owns 32 rows (i), scans the
// block's 512-j slice from LDS. C/D layout (32x32x16): col=lane&31,
// row=(reg&3)+8*(reg>>2)+4*(lane>>5).
// Col-mins per wave -> LDS region, block-combined -> colpart[cloud][chunk][j].
// Row-mins (slice-partial) -> butterfly over 32 lanes -> rowpart.
__global__ __launch_bounds__(256) void cd_mfma(
    const float* __restrict__ pred, const float* __restrict__ targ,
    float* __restrict__ colpart, float* __restrict__ rowpart,
    float* __restrict__ out) {
  __shared__ uint4 Blds4[kJSL * 2];   // 16 KB: swizzled B rows (32 B/point)
  __shared__ float clds[4 * kJSL];    // 8 KB: per-wave col-min regions

  const int t = threadIdx.x;
  const int w = t >> 6, lane = t & 63;
  const int half = lane >> 5, l31 = lane & 31;
  const int chunk = blockIdx.x;      // 0..31 -> 128 rows per block
  const int cloud = blockIdx.y;      // 0..15
  const int slice = blockIdx.z;      // 0..kJS-1

  if ((t | chunk | cloud | slice) == 0) out[0] = 0.0f;  // before cd_reduce

  const u16 one = 0x3F80;

  // ---- A fragment: build per-lane from pred (row arow, k-half `half`) ----
  const int arow = cloud * kN + chunk * 128 + w * 32 + l31;
  union { uint4 u; bf16x8 v; } afu;
  {
    const float a = pred[3 * arow], c = pred[3 * arow + 1], d = pred[3 * arow + 2];
    const u16 ah = bf16_rn(a), ch = bf16_rn(c), dh = bf16_rn(d);
    const u16 al = bf16_rn(a - bf16_f(ah));
    const u16 cl = bf16_rn(c - bf16_f(ch));
    const u16 dl = bf16_rn(d - bf16_f(dh));
    const float s2 = fmaf(a, a, fmaf(c, c, d * d));
    const u16 s2h = bf16_rn(s2);
    const u16 s2l = bf16_rn(s2 - bf16_f(s2h));
    // k 0-7: [xh0,xh1,xh2, xl0,xl1,xl2, xh0,xh1]; k 8-15: [xh2,x2h,x2l,1,1,xl0,xl1,xl2]
    if (half == 0) {
      afu.u.x = pk2(ah, ch); afu.u.y = pk2(dh, al);
      afu.u.z = pk2(cl, dl); afu.u.w = pk2(ah, ch);
    } else {
      afu.u.x = pk2(dh, s2h); afu.u.y = pk2(s2l, one);
      afu.u.z = pk2(one, al); afu.u.w = pk2(cl, dl);
    }
  }
  const bf16x8 afrag = afu.v;

  // ---- Stage B slice (512 points) into LDS, bf16-split, XOR-swizzled ----
  {
    const float* tb = targ + (size_t)(cloud * kN + slice * kJSL) * 3;
    char* bl = (char*)Blds4;
    for (int pl = t; pl < kJSL; pl += 256) {
      const float a = tb[3 * pl], c = tb[3 * pl + 1], d = tb[3 * pl + 2];
      const u16 ah0 = bf16_rn(a), ch0 = bf16_rn(c), dh0 = bf16_rn(d);
      const u16 ah = bf16_rn(-2.0f * bf16_f(ah0));   // exact scale by -2
      const u16 ch = bf16_rn(-2.0f * bf16_f(ch0));
      const u16 dh = bf16_rn(-2.0f * bf16_f(dh0));
      const u16 al = bf16_rn(-2.0f * bf16_f(bf16_rn(a - bf16_f(ah0))));
      const u16 cl = bf16_rn(-2.0f * bf16_f(bf16_rn(c - bf16_f(ch0))));
      const u16 dl = bf16_rn(-2.0f * bf16_f(bf16_rn(d - bf16_f(dh0))));
      const float s2 = fmaf(a, a, fmaf(c, c, d * d));
      const u16 s2h = bf16_rn(s2);
      const u16 s2l = bf16_rn(s2 - bf16_f(s2h));
      // k: 0-2 -2yh, 3-5 -2yh, 6-8 -2yl, 9 one, 10 one, 11 y2h, 12 y2l, 13-15 -2yl
      uint4 w0, w1;
      w0.x = pk2(ah, ch); w0.y = pk2(dh, ah); w0.z = pk2(ch, dh); w0.w = pk2(al, cl);
      w1.x = pk2(dl, one); w1.y = pk2(one, s2h); w1.z = pk2(s2l, al); w1.w = pk2(cl, dl);
      const int sw = (pl & 7) << 4;                 // XOR bit4..6 with point&7
      *reinterpret_cast<uint4*>(bl + ((pl * 32) ^ sw)) = w0;
      *reinterpret_cast<uint4*>(bl + ((pl * 32 + 16) ^ sw)) = w1;
    }
  }
  __syncthreads();

  f32x16 zacc;
#pragma unroll
  for (int r = 0; r < 16; ++r) zacc[r] = 0.0f;
  float rmin[16];
#pragma unroll
  for (int r = 0; r < 16; ++r) rmin[r] = 1e30f;

  constexpr int NT = kJSL / 64;      // 8 iterations, 64 j per iteration
  // Per-lane LDS byte address; swizzle term (l31&7) is jt-invariant since
  // 64 ≡ 0 (mod 8): point = jt*64 + sel*32 + l31 -> point&7 == l31&7.
  const char* bl = (const char*)Blds4;
  int addr0 = (l31 * 32 + half * 16) ^ ((l31 & 7) << 4);
  for (int jt = 0; jt < NT; ++jt) {
    union { uint4 u; bf16x8 v; } B0, B1;
    B0.u = *reinterpret_cast<const uint4*>(bl + addr0);
    B1.u = *reinterpret_cast<const uint4*>(bl + addr0 + 1024);
    addr0 += 2048;
    const f32x16 s0 = __builtin_amdgcn_mfma_f32_32x32x16_bf16(afrag, B0.v, zacc, 0, 0, 0);
    const f32x16 s1 = __builtin_amdgcn_mfma_f32_32x32x16_bf16(afrag, B1.v, zacc, 0, 0, 0);
    // col-min trees over the 16 regs (rows) via v_min3: 8 ops each
    float a0 = min3f(s0[0], s0[1], s0[2]);
    float a1 = min3f(s0[3], s0[4], s0[5]);
    float a2 = min3f(s0[6], s0[7], s0[8]);
    float a3 = min3f(s0[9], s0[10], s0[11]);
    float a4 = min3f(s0[12], s0[13], s0[14]);
    float cm0 = fminf(min3f(a0, a1, a2), min3f(a3, a4, s0[15]));
    float b0t = min3f(s1[0], s1[1], s1[2]);
    float b1t = min3f(s1[3], s1[4], s1[5]);
    float b2t = min3f(s1[6], s1[7], s1[8]);
    float b3t = min3f(s1[9], s1[10], s1[11]);
    float b4t = min3f(s1[12], s1[13], s1[14]);
    float cm1 = fminf(min3f(b0t, b1t, b2t), min3f(b3t, b4t, s1[15]));
    // row-min update: one v_min3 per reg
#pragma unroll
    for (int r = 0; r < 16; ++r)
      asm("v_min3_f32 %0, %0, %1, %2" : "+v"(rmin[r]) : "v"(s0[r]), "v"(s1[r]));
    cm0 = fminf(cm0, __shfl_xor(cm0, 32, 64));   // join the two row-halves
    cm1 = fminf(cm1, __shfl_xor(cm1, 32, 64));
    if (half == 0) {
      clds[w * kJSL + jt * 64 + l31] = cm0;
      clds[w * kJSL + jt * 64 + 32 + l31] = cm1;
    }
  }

  // Slice-partial row-mins: butterfly across the 32 lanes of each half.
#pragma unroll
  for (int st = 1; st < 32; st <<= 1) {
#pragma unroll
    for (int r = 0; r < 16; ++r)
      rmin[r] = fminf(rmin[r], __shfl_xor(rmin[r], st, 64));
  }
  if (l31 == 0) {   // lanes 0 and 32: each holds its half's 16 row-mins
    float* rp = rowpart + ((size_t)slice * kB + cloud) * kN + chunk * 128 + w * 32;
#pragma unroll
    for (int r = 0; r < 16; ++r) {
      const int row = (r & 3) + 8 * (r >> 2) + 4 * half;
      rp[row] = rmin[r];
    }
  }

  __syncthreads();
  for (int j = t; j < kJSL; j += 256) {
    const float m = fminf(fminf(clds[j], clds[kJSL + j]),
                          fminf(clds[2 * kJSL + j], clds[3 * kJSL + j]));
    colpart[((size_t)cloud * 32 + chunk) * kN + slice * kJSL + j] = m;
  }
}

// Per (cloud, p): min over kJS row-slices + min over 32 col-chunks; sum both,
// block-sum -> atomicAdd.
__global__ __launch_bounds__(256) void cd_reduce(
    const float* __restrict__ colpart, const float* __restrict__ rowpart,
    float* __restrict__ out) {
  const int u = blockIdx.x * 256 + threadIdx.x;   // 0..kPlane-1
  const int cloud = u >> 12, p = u & (kN - 1);
  float rm = 1e30f;
#pragma unroll
  for (int s2 = 0; s2 < kJS; ++s2)
    rm = fminf(rm, rowpart[((size_t)s2 * kB + cloud) * kN + p]);
  const float* cp = colpart + (size_t)cloud * 32 * kN + p;
  float cm = 1e30f;
#pragma unroll 8
  for (int c = 0; c < 32; ++c) cm = fminf(cm, cp[(size_t)c * kN]);
  float s = rm + cm;
  for (int o = 32; o > 0; o >>= 1) s += __shfl_down(s, o, 64);
  __shared__ float wsum[4];
  const int lane = threadIdx.x & 63, wv = threadIdx.x >> 6;
  if (lane == 0) wsum[wv] = s;
  __syncthreads();
  if (threadIdx.x == 0)
    atomicAdd(out, (wsum[0] + wsum[1] + wsum[2] + wsum[3]) * kScale);
}

// ---------- fallback (small ws): R5-style pk_fma direct kernel ----------
template <int KX>
__global__ __launch_bounds__(256) void chamfer_direct(
    const float* __restrict__ pred, const float* __restrict__ targ,
    float* __restrict__ out) {
  __shared__ float4 tA[128], tB[128];
  const int t = threadIdx.x;
  const int xb = blockIdx.x, b = blockIdx.y, dir = blockIdx.z;
  const float* __restrict__ X = dir ? targ : pred;
  const float* __restrict__ Y = dir ? pred : targ;
  float2 xx2[KX], xy2[KX], xz2[KX];
  float x2[KX], mn[KX];
  const int ibase = b * kN + xb * (256 * KX) + t;
#pragma unroll
  for (int k = 0; k < KX; ++k) {
    const int i = ibase + k * 256;
    const float a = X[3 * i], c = X[3 * i + 1], d = X[3 * i + 2];
    x2[k] = fmaf(a, a, fmaf(c, c, d * d));
    xx2[k] = make_float2(-2.0f * a, -2.0f * a);
    xy2[k] = make_float2(-2.0f * c, -2.0f * c);
    xz2[k] = make_float2(-2.0f * d, -2.0f * d);
    mn[k] = 1e30f;
  }
  for (int t0 = 0; t0 < kN; t0 += 256) {
    __syncthreads();
    if (t < 128) {
      const int j0 = 3 * (b * kN + t0 + 2 * t);
      const float a0 = Y[j0], c0 = Y[j0 + 1], d0 = Y[j0 + 2];
      const float a1 = Y[j0 + 3], c1 = Y[j0 + 4], d1 = Y[j0 + 5];
      tA[t] = make_float4(a0, a1, c0, c1);
      tB[t] = make_float4(d0, d1, fmaf(a0, a0, fmaf(c0, c0, d0 * d0)),
                          fmaf(a1, a1, fmaf(c1, c1, d1 * d1)));
    }
    __syncthreads();
    for (int jj = 0; jj < 128; ++jj) {
      const float4 qa = tA[jj], qb = tB[jj];
      const float2 qx = make_float2(qa.x, qa.y), qy = make_float2(qa.z, qa.w);
      const float2 qz = make_float2(qb.x, qb.y), qw = make_float2(qb.z, qb.w);
#pragma unroll
      for (int k = 0; k < KX; ++k) {
        float2 acc;
        asm("v_pk_fma_f32 %0, %1, %2, %3\n\t"
            "v_pk_fma_f32 %0, %4, %5, %0\n\t"
            "v_pk_fma_f32 %0, %6, %7, %0"
            : "=&v"(acc)
            : "v"(xz2[k]), "v"(qz), "v"(qw), "v"(xy2[k]), "v"(qy),
              "v"(xx2[k]), "v"(qx));
        asm("v_min3_f32 %0, %0, %1, %2" : "+v"(mn[k]) : "v"(acc.x), "v"(acc.y));
      }
    }
  }
  float s = 0.0f;
#pragma unroll
  for (int k = 0; k < KX; ++k) s += x2[k] + mn[k];
  for (int o = 32; o > 0; o >>= 1) s += __shfl_down(s, o, 64);
  __shared__ float wsum[4];
  const int lane = t & 63, wv = t >> 6;
  if (lane == 0) wsum[wv] = s;
  __syncthreads();
  if (t == 0)
    atomicAdd(out, (wsum[0] + wsum[1] + wsum[2] + wsum[3]) * kScale);
}

}  // namespace

extern "C" void kernel_launch(void* const* d_in, const int* in_sizes, int n_in,
                              void* d_out, int out_size, void* d_ws,
                              size_t ws_size, hipStream_t stream) {
  const float* pred = (const float*)d_in[0];
  const float* targ = (const float*)d_in[1];
  float* out = (float*)d_out;

  const size_t needCol = (size_t)kB * 32 * kN * sizeof(float);   // 8 MB
  const size_t needRow = (size_t)kJS * kPlane * sizeof(float);   // 2 MB
  if (ws_size >= needCol + needRow) {                            // 10 MB
    float* colpart = (float*)d_ws;
    float* rowpart = (float*)((char*)d_ws + needCol);
    cd_mfma<<<dim3(32, kB, kJS), 256, 0, stream>>>(pred, targ, colpart,
                                                   rowpart, out);
    cd_reduce<<<dim3(kPlane / 256), 256, 0, stream>>>(colpart, rowpart, out);
  } else {
    init_out<<<dim3(1), dim3(1), 0, stream>>>(out);
    constexpr int KX = 8;
    dim3 grid(kN / (256 * KX), kB, 2);
    chamfer_direct<KX><<<grid, 256, 0, stream>>>(pred, targ, out);
  }
}

// Round 6
// 94.532 us; speedup vs baseline: 1.0660x; 1.0660x over previous
//
#include <hip/hip_runtime.h>

// Chamfer distance, B=16 clouds x N=4096 x D=3, fp32, via bf16-split MFMA.
// S_ij = d(x_i, y_j) computed by ONE v_mfma_f32_32x32x16_bf16 dot (K=16):
//   A_i = [xh0..2, xl0..2, xh0..2, x2h, x2l, 1, 1, xl0..2]
//   B_j = [-2yh0..2, -2yh0..2, -2yl0..2, 1, 1, y2h, y2l, -2yl0..2]
//   sum_k A_ik B_jk = x^2 + y^2 - 2(xh+xl).(yh+yl)  (abs err <~7e-4)
// History: R8 96.0us (3 kernels, colpart/rowpart). R9/R10 fused-atomics 137us
//   REGRESSION (agent-scope fences). R11 +min3 98.5 NEUTRAL (not VALU-bound).
//   R12 launch_bounds(256,5) FAILED (kernel unschedulable). R13 fused prep
//   +LDS B staging, 2 kernels, 100.8 NEUTRAL. Four structures in 96-101us
//   band; only visible dispatches are harness 268MB poison fills (43us @78%
//   HBM). => window ~= fill + launch overheads + our kernels (<42us each).
// R14: direction-split. Grid (32 chunks, 16 clouds, 2 dirs); dir 0 = pred
//   rows vs targ, dir 1 = targ rows vs pred. Each block scans ALL 4096
//   opposite points via R13's proven LDS staging (8 stages x 512 pts,
//   XOR-swizzled ds_read_b128), keeps ONLY row-mins (16 v_min3/iter; col-min
//   trees, clds, colpart/rowpart, cd_reduce all deleted), butterflies, sums,
//   one atomicAdd per block. MFMA work x2 (~2us total, irrelevant). Zero
//   workspace. This is both the best structure and the floor test: if total
//   stays ~96-100us with cd_fused ~10-15us, the harness window is the floor.

namespace {

constexpr int kB = 16;
constexpr int kN = 4096;
constexpr int kStage = 512;               // points per LDS stage
constexpr int kNS = kN / kStage;          // 8 stages
constexpr float kScale = 1.0f / (float)(kB * kN);

typedef short bf16x8 __attribute__((ext_vector_type(8)));
typedef float f32x16 __attribute__((ext_vector_type(16)));
typedef unsigned short u16;

__device__ inline u16 bf16_rn(float f) {
  union { float f; unsigned u; } v; v.f = f;
  unsigned r = v.u + 0x7fffu + ((v.u >> 16) & 1u);
  return (u16)(r >> 16);
}
__device__ inline float bf16_f(u16 h) {
  union { unsigned u; float f; } v; v.u = (unsigned)h << 16;
  return v.f;
}
__device__ inline unsigned pk2(u16 lo, u16 hi) {
  return (unsigned)lo | ((unsigned)hi << 16);
}

__global__ void init_out(float* out) { out[0] = 0.0f; }

// One block = 4 waves x 32 rows = 128 rows of X (cloud, chunk); scans all
// kN points of Y staged through LDS. C/D layout (32x32x16): col=lane&31,
// row=(reg&3)+8*(reg>>2)+4*(lane>>5). Row-min only; butterfly over the 32
// lanes of each half completes the min over all j; block-sum -> atomicAdd.
__global__ __launch_bounds__(256) void cd_fused(
    const float* __restrict__ pred, const float* __restrict__ targ,
    float* __restrict__ out) {
  __shared__ uint4 Blds4[kStage * 2];   // 16 KB: swizzled B rows (32 B/pt)
  __shared__ float wsum[4];

  const int t = threadIdx.x;
  const int w = t >> 6, lane = t & 63;
  const int half = lane >> 5, l31 = lane & 31;
  const int chunk = blockIdx.x;      // 0..31 -> 128 rows per block
  const int cloud = blockIdx.y;      // 0..15
  const int dir = blockIdx.z;        // 0: pred rows vs targ; 1: swapped
  const float* __restrict__ X = dir ? targ : pred;
  const float* __restrict__ Y = dir ? pred : targ;

  const u16 one = 0x3F80;

  // ---- A fragment: build per-lane from X (row arow, k-half `half`) ----
  const int arow = cloud * kN + chunk * 128 + w * 32 + l31;
  union { uint4 u; bf16x8 v; } afu;
  {
    const float a = X[3 * arow], c = X[3 * arow + 1], d = X[3 * arow + 2];
    const u16 ah = bf16_rn(a), ch = bf16_rn(c), dh = bf16_rn(d);
    const u16 al = bf16_rn(a - bf16_f(ah));
    const u16 cl = bf16_rn(c - bf16_f(ch));
    const u16 dl = bf16_rn(d - bf16_f(dh));
    const float s2 = fmaf(a, a, fmaf(c, c, d * d));
    const u16 s2h = bf16_rn(s2);
    const u16 s2l = bf16_rn(s2 - bf16_f(s2h));
    // k 0-7: [xh0,xh1,xh2, xl0,xl1,xl2, xh0,xh1]
    // k 8-15: [xh2,x2h,x2l,1,1,xl0,xl1,xl2]
    if (half == 0) {
      afu.u.x = pk2(ah, ch); afu.u.y = pk2(dh, al);
      afu.u.z = pk2(cl, dl); afu.u.w = pk2(ah, ch);
    } else {
      afu.u.x = pk2(dh, s2h); afu.u.y = pk2(s2l, one);
      afu.u.z = pk2(one, al); afu.u.w = pk2(cl, dl);
    }
  }
  const bf16x8 afrag = afu.v;

  f32x16 zacc;
#pragma unroll
  for (int r = 0; r < 16; ++r) zacc[r] = 0.0f;
  float rmin[16];
#pragma unroll
  for (int r = 0; r < 16; ++r) rmin[r] = 1e30f;

  const float* yb = Y + (size_t)cloud * kN * 3;
  // Per-lane LDS read address; swizzle term (l31&7) is jt-invariant since
  // point = jt*64 + sel*32 + l31 and 64,32 ≡ 0 (mod 8... 32&7=0? no:
  // 32 mod 8 = 0) -> point&7 == l31&7 for both B0 and B1 streams.
  const int raddr = (l31 * 32 + half * 16) ^ ((l31 & 7) << 4);

  for (int st = 0; st < kNS; ++st) {
    __syncthreads();   // previous compute done before overwriting LDS
    {   // ---- stage 512 points of Y, bf16-split, XOR-swizzled ----
      char* bl = (char*)Blds4;
      for (int pl = t; pl < kStage; pl += 256) {
        const int gp = st * kStage + pl;
        const float a = yb[3 * gp], c = yb[3 * gp + 1], d = yb[3 * gp + 2];
        const u16 ah0 = bf16_rn(a), ch0 = bf16_rn(c), dh0 = bf16_rn(d);
        const u16 ah = bf16_rn(-2.0f * bf16_f(ah0));   // exact scale by -2
        const u16 ch = bf16_rn(-2.0f * bf16_f(ch0));
        const u16 dh = bf16_rn(-2.0f * bf16_f(dh0));
        const u16 al = bf16_rn(-2.0f * bf16_f(bf16_rn(a - bf16_f(ah0))));
        const u16 cl = bf16_rn(-2.0f * bf16_f(bf16_rn(c - bf16_f(ch0))));
        const u16 dl = bf16_rn(-2.0f * bf16_f(bf16_rn(d - bf16_f(dh0))));
        const float s2 = fmaf(a, a, fmaf(c, c, d * d));
        const u16 s2h = bf16_rn(s2);
        const u16 s2l = bf16_rn(s2 - bf16_f(s2h));
        // k: 0-2 -2yh, 3-5 -2yh, 6-8 -2yl, 9 one, 10 one, 11 y2h, 12 y2l,
        //    13-15 -2yl
        uint4 w0, w1;
        w0.x = pk2(ah, ch); w0.y = pk2(dh, ah);
        w0.z = pk2(ch, dh); w0.w = pk2(al, cl);
        w1.x = pk2(dl, one); w1.y = pk2(one, s2h);
        w1.z = pk2(s2l, al); w1.w = pk2(cl, dl);
        const int sw = (pl & 7) << 4;               // XOR bit4..6 w/ point&7
        *reinterpret_cast<uint4*>(bl + ((pl * 32) ^ sw)) = w0;
        *reinterpret_cast<uint4*>(bl + ((pl * 32 + 16) ^ sw)) = w1;
      }
    }
    __syncthreads();

    const char* blc = (const char*)Blds4;
    int addr0 = raddr;
#pragma unroll
    for (int jt = 0; jt < kStage / 64; ++jt) {   // 8 iters, 64 j each
      union { uint4 u; bf16x8 v; } B0, B1;
      B0.u = *reinterpret_cast<const uint4*>(blc + addr0);
      B1.u = *reinterpret_cast<const uint4*>(blc + addr0 + 1024);
      addr0 += 2048;
      const f32x16 s0 =
          __builtin_amdgcn_mfma_f32_32x32x16_bf16(afrag, B0.v, zacc, 0, 0, 0);
      const f32x16 s1 =
          __builtin_amdgcn_mfma_f32_32x32x16_bf16(afrag, B1.v, zacc, 0, 0, 0);
      // row-min update only: one v_min3 per reg
#pragma unroll
      for (int r = 0; r < 16; ++r)
        asm("v_min3_f32 %0, %0, %1, %2"
            : "+v"(rmin[r]) : "v"(s0[r]), "v"(s1[r]));
    }
  }

  // Complete row-mins: butterfly across the 32 lanes of each half.
#pragma unroll
  for (int st = 1; st < 32; st <<= 1) {
#pragma unroll
    for (int r = 0; r < 16; ++r)
      rmin[r] = fminf(rmin[r], __shfl_xor(rmin[r], st, 64));
  }
  // Each half's lanes now hold identical 16 full row-mins (rows
  // {(r&3)+8*(r>>2)+4*half} of the wave's 32); halves partition the rows.
  float s = 0.0f;
#pragma unroll
  for (int r = 0; r < 16; ++r) s += rmin[r];
  s = (l31 == 0) ? s : 0.0f;        // one contributor per half
  s += __shfl_down(s, 32, 64);      // lane 0 <- both halves
  if (lane == 0) wsum[w] = s;
  __syncthreads();
  if (t == 0)
    atomicAdd(out, (wsum[0] + wsum[1] + wsum[2] + wsum[3]) * kScale);
}

}  // namespace

extern "C" void kernel_launch(void* const* d_in, const int* in_sizes, int n_in,
                              void* d_out, int out_size, void* d_ws,
                              size_t ws_size, hipStream_t stream) {
  const float* pred = (const float*)d_in[0];
  const float* targ = (const float*)d_in[1];
  float* out = (float*)d_out;
  (void)d_ws; (void)ws_size;

  init_out<<<dim3(1), dim3(1), 0, stream>>>(out);
  cd_fused<<<dim3(32, kB, 2), 256, 0, stream>>>(pred, targ, out);
}